// Round 1
// 633.818 us; speedup vs baseline: 1.1506x; 1.1506x over previous
//
#include <hip/hip_runtime.h>
#include <math.h>

#define BB 32
#define DD 128
#define TLEN 4096
#define NSEG 512
#define HOP 256
#define NFR 17
#define NBINS 257
#define STOT 4369
#define NPATCH 196
#define NFREQ 99
#define OLAL 4608

// workspace layout (float offsets)
#define FBT2_OFF 0
#define FBT2_SZ  (DD * NFR * NBINS * 2)       // 1,118,464
#define GBUF_OFF (FBT2_OFF + FBT2_SZ)
#define GATE_OFF (GBUF_OFF + BB * DD)
#define ZI_OFF   (GATE_OFF + BB * DD)
#define ZI_SZ    (BB * NFREQ * DD * 2)        // 811,008
#define X0I_OFF  (ZI_OFF + ZI_SZ)
#define X0I_SZ   (BB * NPATCH * DD)           // 802,816
#define XT_OFF   (X0I_OFF + X0I_SZ)
#define WF_OFF   (XT_OFF + BB * DD * TLEN)    // bf16 hi/lo weight fragments (4 mats x 32768 ushort)

typedef __attribute__((ext_vector_type(8))) short bf16x8;
typedef __attribute__((ext_vector_type(4))) float f32x4;
typedef __attribute__((ext_vector_type(8))) unsigned short u16x8;

__device__ __forceinline__ float gelu_exact(float x) {
    return 0.5f * x * (1.0f + erff(x * 0.70710678118654752f));
}

__device__ __forceinline__ short bf16_rne(float v) {
    unsigned b = __float_as_uint(v);
    return (short)((b + 0x7fffu + ((b >> 16) & 1u)) >> 16);
}

// split fp32 -> bf16 hi + bf16 lo (v ~= hi + lo, error ~2^-17 relative)
__device__ __forceinline__ void split8(float4 a, float4 b, bf16x8& hi, bf16x8& lo) {
    float v[8] = {a.x, a.y, a.z, a.w, b.x, b.y, b.z, b.w};
#pragma unroll
    for (int e = 0; e < 8; ++e) {
        unsigned bv = __float_as_uint(v[e]);
        unsigned hb = (bv + 0x7fffu + ((bv >> 16) & 1u)) & 0xffff0000u;
        float hf = __uint_as_float(hb);
        hi[e] = (short)(hb >> 16);
        lo[e] = bf16_rne(v[e] - hf);
    }
}

// ---------------------------------------------------------------- zero gbuf
__global__ __launch_bounds__(256) void zero_kernel(float* p, int n) {
    int i = blockIdx.x * 256 + threadIdx.x;
    if (i < n) p[i] = 0.0f;
}

// ---------------------------------------------------- pack w1/w2 MFMA frags
// layout (per matrix, 32768 ushort): [hi: ((kt*8+n)*64+lane)*8][lo: same +16384]
// element e of lane: w[(kt*32 + (lane>>4)*8 + e)*128 + n*16 + (lane&15)]
__global__ __launch_bounds__(256) void prep_wfrag(
    const float* __restrict__ w0, const float* __restrict__ w1,
    const float* __restrict__ w2, const float* __restrict__ w3,
    unsigned short* __restrict__ outw) {
    int id = blockIdx.x * 256 + threadIdx.x;
    if (id >= 4 * 2048) return;
    int m = id >> 11;
    int r = id & 2047;                 // (kt, n, lane)
    int kt = r >> 9;
    int n = (r >> 6) & 7;
    int lane = r & 63;
    int k0 = kt * 32 + (lane >> 4) * 8;
    int col = n * 16 + (lane & 15);
    const float* w = (m == 0) ? w0 : (m == 1) ? w1 : (m == 2) ? w2 : w3;
    u16x8 hi, lo;
#pragma unroll
    for (int e = 0; e < 8; ++e) {
        float v = w[(size_t)(k0 + e) * DD + col];
        unsigned bv = __float_as_uint(v);
        unsigned hb = (bv + 0x7fffu + ((bv >> 16) & 1u)) & 0xffff0000u;
        float hf = __uint_as_float(hb);
        float lres = v - hf;
        unsigned bl = __float_as_uint(lres);
        hi[e] = (unsigned short)(hb >> 16);
        lo[e] = (unsigned short)((bl + 0x7fffu + ((bl >> 16) & 1u)) >> 16);
    }
    u16x8* base = (u16x8*)(outw + (size_t)m * 32768);
    base[r] = hi;
    base[2048 + r] = lo;
}

// ------------------------------------------------- tfb -> fbt2 (D,17,257,2)
__global__ __launch_bounds__(256) void prep_fb(const float* __restrict__ tfb,
                                               float* __restrict__ fbt2) {
    int idx = blockIdx.x * 256 + threadIdx.x;
    if (idx >= STOT * DD) return;
    int d = idx & 127;
    int s = idx >> 7;
    float2 a = ((const float2*)tfb)[s * DD + d];
    float2 b = ((const float2*)tfb)[STOT * DD + s * DD + d];
    int f = s / NFR, t = s % NFR;
    float2 r;
    r.x = -(a.x + b.x);
    r.y = -(a.y + b.y);
    ((float2*)fbt2)[((size_t)d * NFR + t) * NBINS + f] = r;
}

// ------------------------------------------------- ecg (B,T,D) -> (B,D,T)
__global__ __launch_bounds__(256) void transpose_btd(const float* __restrict__ in,
                                                     float* __restrict__ out) {
    __shared__ float tile[32][33];
    int b = blockIdx.z;
    int t0 = blockIdx.x * 32;
    int d0 = blockIdx.y * 32;
    int lx = threadIdx.x;
    int ly = threadIdx.y;
    for (int i = ly; i < 32; i += 8)
        tile[i][lx] = in[((size_t)b * TLEN + t0 + i) * DD + d0 + lx];
    __syncthreads();
    for (int i = ly; i < 32; i += 8)
        out[((size_t)b * DD + d0 + i) * TLEN + t0 + lx] = tile[lx][i];
}

// ---------------------------------------- image rfft(ortho) + filter + g acc
__global__ __launch_bounds__(128) void img_dft(const float* __restrict__ image,
                                               const float* __restrict__ ifb,
                                               const float* __restrict__ sel,
                                               float* __restrict__ zi,
                                               float* __restrict__ gbuf) {
    __shared__ float ctab[NPATCH], stab[NPATCH];
    int b = blockIdx.x / 11;
    int fg = blockIdx.x % 11;
    int d = threadIdx.x;
    for (int m = d; m < NPATCH; m += 128) {
        ctab[m] = cospif(m * (2.0f / 196.0f));
        stab[m] = sinpif(m * (2.0f / 196.0f));
    }
    __syncthreads();
    float accr[9], acci[9];
    int mc[9];
#pragma unroll
    for (int j = 0; j < 9; ++j) { accr[j] = 0.0f; acci[j] = 0.0f; mc[j] = 0; }
    const float* img = image + (size_t)b * NPATCH * DD + d;
    for (int n = 0; n < NPATCH; ++n) {
        float v = img[(size_t)n * DD];
#pragma unroll
        for (int j = 0; j < 9; ++j) {
            float c = ctab[mc[j]], s = stab[mc[j]];
            accr[j] += v * c;
            acci[j] -= v * s;
            mc[j] += fg * 9 + j;
            if (mc[j] >= NPATCH) mc[j] -= NPATCH;
        }
    }
    float gg = 0.0f;
#pragma unroll
    for (int j = 0; j < 9; ++j) {
        int f = fg * 9 + j;
        float Xr = accr[j] * (1.0f / 14.0f);
        float Xi = acci[j] * (1.0f / 14.0f);
        float sr = (Xr * Xr - Xi * Xi) * (1.0f / 99.0f);
        float si = 2.0f * Xr * Xi * (1.0f / 99.0f);
        float2 f0 = ((const float2*)ifb)[f * DD + d];
        float2 f1 = ((const float2*)ifb)[NFREQ * DD + f * DD + d];
        float fbr = -(f0.x + f1.x), fbi = -(f0.y + f1.y);
        float zr = sr * fbr - si * fbi;
        float zm = sr * fbi + si * fbr;
        float2 o; o.x = zr; o.y = zm;
        ((float2*)zi)[((size_t)b * NFREQ + f) * DD + d] = o;
        float2 sl = ((const float2*)sel)[f * DD + d];
        gg += zr * sl.x - zm * sl.y;
    }
    atomicAdd(gbuf + b * DD + d, gg * (1.0f / 99.0f));
}

// ----------------------------------------------------- gate = g @ w^T + b
__global__ __launch_bounds__(128) void gate_kernel(const float* __restrict__ gbuf,
                                                   const float* __restrict__ w,
                                                   const float* __restrict__ bias,
                                                   float* __restrict__ gate) {
    __shared__ float gs[DD];
    int b = blockIdx.x, e = threadIdx.x;
    gs[e] = gbuf[b * DD + e];
    __syncthreads();
    float acc = bias[e];
    const float* wr = w + (size_t)e * DD;
    for (int d = 0; d < DD; ++d) acc += gs[d] * wr[d];
    gate[b * DD + e] = acc;
}

// ------------------------- per-(b,d): STFT -> filter*gate -> ISTFT, in-place
#define SKN 264
#define SK(i) ((i) + ((i) >> 5))

__global__ __launch_bounds__(256, 4) void stft_filter_istft(
    float* xT, const float* __restrict__ fbt2, const float* __restrict__ gate) {
    __shared__ float ar[NFR * SKN];
    __shared__ float ai[NFR * SKN];
    __shared__ float win[NSEG];
    __shared__ float twc[128], tws[128];
    int tid = threadIdx.x;
    int bd = blockIdx.x;
    int d = bd & 127;
    float gat = gate[bd];
    const float scl = gat * (1.0f / 4369.0f);
    float* xrow = xT + (size_t)bd * TLEN;
    const float2* fbrow = (const float2*)(fbt2 + (size_t)d * NFR * NBINS * 2);

    for (int j = tid; j < NSEG; j += 256)
        win[j] = 0.5f - 0.5f * cospif(j * (1.0f / 256.0f));
    if (tid < 128) {
        twc[tid] = cospif(tid * (1.0f / 128.0f));
        tws[tid] = -sinpif(tid * (1.0f / 128.0f));
    }
    __syncthreads();

    for (int t = 0; t < NFR; ++t) {
        int m = tid;
        int src = t * HOP + 2 * m - HOP;
        float e = 0.0f, o = 0.0f;
        if (src >= 0 && src < TLEN) {
            float2 v = *(const float2*)(xrow + src);
            e = v.x; o = v.y;
        }
        e *= win[2 * m]; o *= win[2 * m + 1];
        int r = __brev((unsigned)m) >> 24;
        ar[t * SKN + SK(r)] = e;
        ai[t * SKN + SK(r)] = o;
    }

    for (int s = 1; s <= 8; ++s) {
        __syncthreads();
        int half = 1 << (s - 1);
        for (int j = tid; j < NFR * 128; j += 256) {
            int t = j >> 7, m = j & 127;
            int base = t * SKN;
            int k = m & (half - 1);
            int p = ((m >> (s - 1)) << s) + k;
            int twi = k << (8 - s);
            float c = twc[twi], sn = tws[twi];
            int a0 = base + SK(p), a1 = base + SK(p + half);
            float ur = ar[a0], ui = ai[a0];
            float vr = ar[a1], vi = ai[a1];
            float tr = vr * c - vi * sn;
            float ti = vr * sn + vi * c;
            ar[a0] = ur + tr; ai[a0] = ui + ti;
            ar[a1] = ur - tr; ai[a1] = ui - ti;
        }
    }
    __syncthreads();

    float y1r[9], y1i[9], y2r[9], y2i[9];
#pragma unroll
    for (int it = 0; it < 9; ++it) {
        int j = tid + it * 256;
        if (j < NFR * 129) {
            int t = j / 129, m = j - t * 129;
            int base = t * SKN;
            const float2* fbr = fbrow + t * NBINS;
            if (m == 0) {
                float re = ar[base + SK(0)], im = ai[base + SK(0)];
                float z0 = (re + im) * (1.0f / 256.0f);
                float zN = (re - im) * (1.0f / 256.0f);
                float2 fb0 = fbr[0], fbN = fbr[256];
                y1r[it] = z0 * z0 * fb0.x * scl; y1i[it] = 0.0f;
                y2r[it] = zN * zN * fbN.x * scl; y2i[it] = 0.0f;
            } else if (m == 128) {
                float Zr = ar[base + SK(128)], Zi = ai[base + SK(128)];
                float zr = Zr * (1.0f / 256.0f), zi2 = -Zi * (1.0f / 256.0f);
                float sr = zr * zr - zi2 * zi2, si = 2.0f * zr * zi2;
                float2 fb = fbr[128];
                y1r[it] = (sr * fb.x - si * fb.y) * scl;
                y1i[it] = (sr * fb.y + si * fb.x) * scl;
                y2r[it] = 0.0f; y2i[it] = 0.0f;
            } else {
                float Amr = ar[base + SK(m)],       Ami = ai[base + SK(m)];
                float Acr = ar[base + SK(256 - m)], Aci = ai[base + SK(256 - m)];
                float c = cospif(m * (1.0f / 256.0f));
                float sn = sinpif(m * (1.0f / 256.0f));
                {
                    float Br = Acr, Bi = -Aci;
                    float xer = 0.5f * (Amr + Br), xei = 0.5f * (Ami + Bi);
                    float xo_r = 0.5f * (Ami - Bi), xo_i = -0.5f * (Amr - Br);
                    float Xr = xer + c * xo_r + sn * xo_i;
                    float Xi = xei + c * xo_i - sn * xo_r;
                    float zr = Xr * (1.0f / 256.0f), zi2 = Xi * (1.0f / 256.0f);
                    float sr = zr * zr - zi2 * zi2, si = 2.0f * zr * zi2;
                    float2 fb = fbr[m];
                    y1r[it] = (sr * fb.x - si * fb.y) * scl;
                    y1i[it] = (sr * fb.y + si * fb.x) * scl;
                }
                {
                    float Br = Amr, Bi = -Ami;
                    float xer = 0.5f * (Acr + Br), xei = 0.5f * (Aci + Bi);
                    float xo_r = 0.5f * (Aci - Bi), xo_i = -0.5f * (Acr - Br);
                    float Xr = xer - c * xo_r + sn * xo_i;
                    float Xi = xei - c * xo_i - sn * xo_r;
                    float zr = Xr * (1.0f / 256.0f), zi2 = Xi * (1.0f / 256.0f);
                    float sr = zr * zr - zi2 * zi2, si = 2.0f * zr * zi2;
                    float2 fb = fbr[256 - m];
                    y2r[it] = (sr * fb.x - si * fb.y) * scl;
                    y2i[it] = (sr * fb.y + si * fb.x) * scl;
                }
            }
        }
    }
    __syncthreads();

#pragma unroll
    for (int it = 0; it < 9; ++it) {
        int j = tid + it * 256;
        if (j < NFR * 129) {
            int t = j / 129, m = j - t * 129;
            int base = t * SKN;
            if (m == 0) {
                float Er = 0.5f * (y1r[it] + y2r[it]);
                float Dr = 0.5f * (y1r[it] - y2r[it]);
                ar[base + SK(0)] = Er;
                ai[base + SK(0)] = -Dr;
            } else if (m == 128) {
                ar[base + SK(1)] = y1r[it];
                ai[base + SK(1)] = y1i[it];
            } else {
                float c = cospif(m * (1.0f / 256.0f));
                float sn = sinpif(m * (1.0f / 256.0f));
                float Er = 0.5f * (y1r[it] + y2r[it]);
                float Ei = 0.5f * (y1i[it] - y2i[it]);
                float Dr = 0.5f * (y1r[it] - y2r[it]);
                float Di = 0.5f * (y1i[it] + y2i[it]);
                float Or = Dr * c - Di * sn;
                float Oi = Dr * sn + Di * c;
                int r1 = __brev((unsigned)m) >> 24;
                ar[base + SK(r1)] = Er - Oi;
                ai[base + SK(r1)] = -(Ei + Or);
                int r2 = __brev((unsigned)(256 - m)) >> 24;
                ar[base + SK(r2)] = Er + Oi;
                ai[base + SK(r2)] = Ei - Or;
            }
        }
    }

    for (int s = 1; s <= 8; ++s) {
        __syncthreads();
        int half = 1 << (s - 1);
        for (int j = tid; j < NFR * 128; j += 256) {
            int t = j >> 7, m = j & 127;
            int base = t * SKN;
            int k = m & (half - 1);
            int p = ((m >> (s - 1)) << s) + k;
            int twi = k << (8 - s);
            float c = twc[twi], sn = tws[twi];
            int a0 = base + SK(p), a1 = base + SK(p + half);
            float ur = ar[a0], ui = ai[a0];
            float vr = ar[a1], vi = ai[a1];
            float tr = vr * c - vi * sn;
            float ti = vr * sn + vi * c;
            ar[a0] = ur + tr; ai[a0] = ui + ti;
            ar[a1] = ur - tr; ai[a1] = ui - ti;
        }
    }
    __syncthreads();

    for (int j = tid; j < TLEN; j += 256) {
        int p = j + HOP;
        int t1 = p >> 8;
        int t0 = t1 - 1;
        int i1 = p & 255;
        int i0 = i1 + 256;
        int h1 = t1 * SKN + SK(i1 >> 1);
        int h0 = t0 * SKN + SK(i0 >> 1);
        float v1, v0;
        if (j & 1) { v1 = -ai[h1]; v0 = -ai[h0]; }
        else       { v1 =  ar[h1]; v0 =  ar[h0]; }
        float s = v0 * win[i0] + v1 * win[i1];
        float s2 = win[i1];
        float c2 = 1.0f - s2;
        xrow[j] = s / (s2 * s2 + c2 * c2);
    }
}

// ------------------------------------------- image irfft(ortho) + add image
__global__ __launch_bounds__(128) void img_irfft(const float* __restrict__ zi,
                                                 const float* __restrict__ image,
                                                 float* __restrict__ x0img) {
    __shared__ float ctab[NPATCH], stab[NPATCH];
    int b = blockIdx.x / 14;
    int ng = blockIdx.x % 14;
    int d = threadIdx.x;
    for (int m = d; m < NPATCH; m += 128) {
        ctab[m] = cospif(m * (2.0f / 196.0f));
        stab[m] = sinpif(m * (2.0f / 196.0f));
    }
    __syncthreads();
    const float2* zrow = (const float2*)zi + (size_t)b * NFREQ * DD + d;
    float acc[14];
    int mc[14];
    float2 z0 = zrow[0];
#pragma unroll
    for (int j = 0; j < 14; ++j) { acc[j] = z0.x; mc[j] = 0; }
    for (int f = 1; f <= 97; ++f) {
        float2 z = zrow[(size_t)f * DD];
#pragma unroll
        for (int j = 0; j < 14; ++j) {
            int n = ng * 14 + j;
            mc[j] += n;
            if (mc[j] >= NPATCH) mc[j] -= NPATCH;
            acc[j] += 2.0f * (z.x * ctab[mc[j]] - z.y * stab[mc[j]]);
        }
    }
    float2 z98 = zrow[98 * (size_t)DD];
#pragma unroll
    for (int j = 0; j < 14; ++j) {
        int n = ng * 14 + j;
        float a = acc[j] + ((n & 1) ? -z98.x : z98.x);
        float y = a * (1.0f / 14.0f);
        size_t idx = ((size_t)b * NPATCH + n) * DD + d;
        x0img[idx] = y + image[idx];
    }
}

// ------------------------------- addnorm: LN1 -> MLP via split-bf16 MFMA -> LN2
// 64 rows/block, 4 waves: wave w owns rows [w*16, w*16+16), all 128 cols.
// GEMM: D = X(64x128) @ W(128x128) with mfma_f32_16x16x32_bf16.
//   A frag: row = lane&15 (+ w*16), k = kt*32 + 8*(lane>>4)+e (contiguous 16B in LDS).
//   B frag: pre-packed by prep_wfrag (hi/lo), coalesced 16B/lane loads, L2-resident.
//   C/D:    col = lane&15, row = 4*(lane>>4)+reg  [m89-verified layout].
// Split-bf16: acc += Ahi*Bhi + Alo*Bhi + Ahi*Blo  (error ~2^-17, fp32-equivalent).
// LN2 stats via 16-lane shfl_xor butterfly (each row's 128 cols live in one group).
#define XLNS 132

__device__ __forceinline__ void mlp_gemm(const float* __restrict__ ax,
                                         const unsigned short* __restrict__ wf,
                                         int lane, f32x4 acc[8]) {
#pragma unroll
    for (int n = 0; n < 8; ++n) acc[n] = (f32x4){0.f, 0.f, 0.f, 0.f};
    const bf16x8* bh0 = (const bf16x8*)wf;
    const bf16x8* bl0 = (const bf16x8*)(wf + 16384);
#pragma unroll 1
    for (int kt = 0; kt < 4; ++kt) {
        float4 va = *(const float4*)(ax + kt * 32);
        float4 vb = *(const float4*)(ax + kt * 32 + 4);
        bf16x8 ahi, alo;
        split8(va, vb, ahi, alo);
        const bf16x8* bh = bh0 + kt * 512 + lane;
        const bf16x8* bl = bl0 + kt * 512 + lane;
#pragma unroll
        for (int n = 0; n < 8; ++n) {
            bf16x8 wh = bh[n * 64];
            bf16x8 wl = bl[n * 64];
            acc[n] = __builtin_amdgcn_mfma_f32_16x16x32_bf16(ahi, wh, acc[n], 0, 0, 0);
            acc[n] = __builtin_amdgcn_mfma_f32_16x16x32_bf16(alo, wh, acc[n], 0, 0, 0);
            acc[n] = __builtin_amdgcn_mfma_f32_16x16x32_bf16(ahi, wl, acc[n], 0, 0, 0);
        }
    }
}

template <int FUSED>
__global__ __launch_bounds__(256) void addnorm_kernel(
    const float* __restrict__ srcA, const float* __restrict__ srcB,
    const float* __restrict__ ln1g, const float* __restrict__ ln1b,
    const unsigned short* __restrict__ w1f, const float* __restrict__ b1,
    const unsigned short* __restrict__ w2f, const float* __restrict__ b2,
    const float* __restrict__ ln2g, const float* __restrict__ ln2b,
    float* __restrict__ out) {
    __shared__ __align__(16) float xln[64 * XLNS];   // reused: x -> g
    int tid = threadIdx.x;
    int b = 0, t0 = 0;
    size_t R0 = 0;
    // ---- Phase A: build x0
    if (FUSED) {
        b = blockIdx.x >> 6;
        t0 = (blockIdx.x & 63) * 64;
        for (int i = tid; i < 64 * 128; i += 256) {
            int dd = i >> 6, r = i & 63;
            xln[r * XLNS + dd] = srcA[((size_t)b * DD + dd) * TLEN + t0 + r];
        }
        __syncthreads();
        for (int i = tid; i < 64 * 128; i += 256) {
            int r = i >> 7, dd = i & 127;
            xln[r * XLNS + dd] += srcB[((size_t)b * TLEN + t0 + r) * DD + dd];
        }
    } else {
        R0 = (size_t)blockIdx.x * 64;
        for (int i = tid; i < 64 * 128; i += 256) {
            int r = i >> 7, dd = i & 127;
            xln[r * XLNS + dd] = srcA[(R0 + r) * DD + dd];
        }
    }
    __syncthreads();
    // ---- LN1 (wave per row)
    int wave = tid >> 6, lane = tid & 63;
    for (int r = wave; r < 64; r += 4) {
        float v0 = xln[r * XLNS + lane];
        float v1 = xln[r * XLNS + 64 + lane];
        float s = v0 + v1, ss = v0 * v0 + v1 * v1;
        for (int off = 32; off > 0; off >>= 1) {
            s += __shfl_xor(s, off);
            ss += __shfl_xor(ss, off);
        }
        float mean = s * (1.0f / 128.0f);
        float var = ss * (1.0f / 128.0f) - mean * mean;
        float rstd = rsqrtf(var + 1e-5f);
        xln[r * XLNS + lane] = (v0 - mean) * rstd * ln1g[lane] + ln1b[lane];
        xln[r * XLNS + 64 + lane] = (v1 - mean) * rstd * ln1g[64 + lane] + ln1b[64 + lane];
    }
    __syncthreads();
    // ---- fragment coordinates
    int q = lane >> 4, c = lane & 15;
    int rbase = wave * 16 + q * 4;                         // C-frag rows (4)
    const float* ax = &xln[(wave * 16 + c) * XLNS + q * 8]; // A-frag base
    // ---- GEMM1: acc = x @ w1
    f32x4 acc[8];
    mlp_gemm(ax, w1f, lane, acc);
    // ---- residual (post-LN1 x) at this thread's C positions
    float res[8][4];
#pragma unroll
    for (int n = 0; n < 8; ++n)
#pragma unroll
        for (int r = 0; r < 4; ++r)
            res[n][r] = xln[(rbase + r) * XLNS + n * 16 + c];
    // ---- bias + gelu
#pragma unroll
    for (int n = 0; n < 8; ++n) {
        float bb = b1[n * 16 + c];
#pragma unroll
        for (int r = 0; r < 4; ++r)
            acc[n][r] = gelu_exact(acc[n][r] + bb);
    }
    __syncthreads();   // all reads of xln(=x) done
#pragma unroll
    for (int n = 0; n < 8; ++n)
#pragma unroll
        for (int r = 0; r < 4; ++r)
            xln[(rbase + r) * XLNS + n * 16 + c] = acc[n][r];   // xln := g
    __syncthreads();
    // ---- GEMM2: acc = g @ w2; h = acc + b2 + res
    mlp_gemm(ax, w2f, lane, acc);
#pragma unroll
    for (int n = 0; n < 8; ++n) {
        float bb = b2[n * 16 + c];
#pragma unroll
        for (int r = 0; r < 4; ++r)
            acc[n][r] += bb + res[n][r];
    }
    // ---- LN2 stats: rows live in 16-lane groups (cols spread over c and n)
    float s4[4] = {0.f, 0.f, 0.f, 0.f}, ss4[4] = {0.f, 0.f, 0.f, 0.f};
#pragma unroll
    for (int n = 0; n < 8; ++n)
#pragma unroll
        for (int r = 0; r < 4; ++r) {
            float h = acc[n][r];
            s4[r] += h; ss4[r] += h * h;
        }
#pragma unroll
    for (int off = 8; off > 0; off >>= 1) {
#pragma unroll
        for (int r = 0; r < 4; ++r) {
            s4[r] += __shfl_xor(s4[r], off);
            ss4[r] += __shfl_xor(ss4[r], off);
        }
    }
    float g2v[8], b2v[8];
#pragma unroll
    for (int n = 0; n < 8; ++n) {
        g2v[n] = ln2g[n * 16 + c];
        b2v[n] = ln2b[n * 16 + c];
    }
#pragma unroll
    for (int r = 0; r < 4; ++r) {
        float mean = s4[r] * (1.0f / 128.0f);
        float var = ss4[r] * (1.0f / 128.0f) - mean * mean;
        float rstd = rsqrtf(var + 1e-5f);
        size_t orow = FUSED ? ((size_t)b * TLEN + t0 + rbase + r) * DD
                            : (R0 + rbase + r) * DD;
#pragma unroll
        for (int n = 0; n < 8; ++n)
            out[orow + n * 16 + c] = (acc[n][r] - mean) * rstd * g2v[n] + b2v[n];
    }
}

extern "C" void kernel_launch(void* const* d_in, const int* in_sizes, int n_in,
                              void* d_out, int out_size, void* d_ws, size_t ws_size,
                              hipStream_t stream) {
    (void)in_sizes; (void)n_in; (void)out_size; (void)ws_size;
    const float* ecg   = (const float*)d_in[0];
    const float* image = (const float*)d_in[1];
    const float* tfb   = (const float*)d_in[2];
    const float* ifb   = (const float*)d_in[3];
    const float* sel   = (const float*)d_in[4];
    const float* i2t_w = (const float*)d_in[5];
    const float* i2t_b = (const float*)d_in[6];
    const float* t_ln1_g = (const float*)d_in[7];
    const float* t_ln1_b = (const float*)d_in[8];
    const float* t_w1 = (const float*)d_in[9];
    const float* t_b1 = (const float*)d_in[10];
    const float* t_w2 = (const float*)d_in[11];
    const float* t_b2 = (const float*)d_in[12];
    const float* t_ln2_g = (const float*)d_in[13];
    const float* t_ln2_b = (const float*)d_in[14];
    const float* i_ln1_g = (const float*)d_in[15];
    const float* i_ln1_b = (const float*)d_in[16];
    const float* i_w1 = (const float*)d_in[17];
    const float* i_b1 = (const float*)d_in[18];
    const float* i_w2 = (const float*)d_in[19];
    const float* i_b2 = (const float*)d_in[20];
    const float* i_ln2_g = (const float*)d_in[21];
    const float* i_ln2_b = (const float*)d_in[22];
    float* out = (float*)d_out;
    float* ws = (float*)d_ws;
    unsigned short* wfb = (unsigned short*)(ws + WF_OFF);

    zero_kernel<<<16, 256, 0, stream>>>(ws + GBUF_OFF, BB * DD);
    prep_wfrag<<<32, 256, 0, stream>>>(t_w1, t_w2, i_w1, i_w2, wfb);
    prep_fb<<<(STOT * DD + 255) / 256, 256, 0, stream>>>(tfb, ws + FBT2_OFF);
    {
        dim3 tb(32, 8);
        dim3 tg(TLEN / 32, DD / 32, BB);
        transpose_btd<<<tg, tb, 0, stream>>>(ecg, ws + XT_OFF);
    }
    img_dft<<<BB * 11, 128, 0, stream>>>(image, ifb, sel, ws + ZI_OFF, ws + GBUF_OFF);
    gate_kernel<<<BB, 128, 0, stream>>>(ws + GBUF_OFF, i2t_w, i2t_b, ws + GATE_OFF);
    stft_filter_istft<<<BB * DD, 256, 0, stream>>>(ws + XT_OFF, ws + FBT2_OFF, ws + GATE_OFF);
    addnorm_kernel<1><<<BB * (TLEN / 64), 256, 0, stream>>>(
        ws + XT_OFF, ecg, t_ln1_g, t_ln1_b, wfb + 0, t_b1, wfb + 32768, t_b2,
        t_ln2_g, t_ln2_b, out);
    img_irfft<<<BB * 14, 128, 0, stream>>>(ws + ZI_OFF, image, ws + X0I_OFF);
    addnorm_kernel<0><<<(BB * NPATCH) / 64, 256, 0, stream>>>(
        ws + X0I_OFF, nullptr, i_ln1_g, i_ln1_b, wfb + 65536, i_b1, wfb + 98304, i_b2,
        i_ln2_g, i_ln2_b, out + (size_t)BB * TLEN * DD);
}